// Round 2
// baseline (195.104 us; speedup 1.0000x reference)
//
#include <hip/hip_runtime.h>

// QuantizedActorMLP: x(1M,17) -> quant -> L1(17->64)+quantact -> L2(64->64)+quantact -> L3(64->6)
// Integer-exact bf16 MFMA (ints |n|<=127 exact in bf16, sums < 2^24 exact in fp32 acc).
// R2: coalesced async global->LDS staging of x (double-buffered, 1 barrier/iter),
//     med3 clamp + v_perm bf16 packing in epilogues.

typedef __attribute__((ext_vector_type(8))) short short8;    // MFMA A/B frag (8 bf16)
typedef __attribute__((ext_vector_type(4))) float floatx4;   // MFMA C/D frag
typedef __attribute__((ext_vector_type(4))) unsigned int uint4v;
typedef unsigned int uint;

__device__ __forceinline__ uint f32bits(float v) { union { float f; uint u; } c; c.f = v; return c.u; }
__device__ __forceinline__ short bf16i(float v) { return (short)(f32bits(v) >> 16); }
// pack two integer-valued f32 -> two bf16 in one uint (low = z0): one v_perm_b32
__device__ __forceinline__ uint pack2(float z0, float z1) {
  return __builtin_amdgcn_perm(f32bits(z1), f32bits(z0), 0x07060302u);
}
// round-to-nearest-even integer clamped to [-127,127]: v_med3 + v_rndne
__device__ __forceinline__ float qclamp(float v) {
  return __builtin_rintf(__builtin_amdgcn_fmed3f(v, -127.f, 127.f));
}

__device__ __forceinline__ void async_cp16(const float* g, float* l) {
  __builtin_amdgcn_global_load_lds((const __attribute__((address_space(1))) void*)g,
                                   (__attribute__((address_space(3))) void*)l, 16, 0, 0);
}
__device__ __forceinline__ void async_cp4(const float* g, float* l) {
  __builtin_amdgcn_global_load_lds((const __attribute__((address_space(1))) void*)g,
                                   (__attribute__((address_space(3))) void*)l, 4, 0, 0);
}

__global__ void __launch_bounds__(256, 4) qmlp_fused(
    const float* __restrict__ x,
    const float* __restrict__ W1, const float* __restrict__ b1,
    const float* __restrict__ W2, const float* __restrict__ b2,
    const float* __restrict__ W3, const float* __restrict__ b3,
    float* __restrict__ out, int B)
{
  constexpr float QMAXF = 127.0f;
  constexpr float SCALE = 1.33f;
  const float step  = SCALE / QMAXF;
  const float istep = QMAXF / SCALE;

  __shared__ __align__(16) float xs[2][1088];   // 64 rows x 17 floats, double-buffered
  __shared__ float red[256];
  __shared__ float sc_sh[3];
  const int tid = threadIdx.x;

  // ---- per-tensor weight scales s = max|W|/127 ----
  {
    float m = 0.f;
    for (int i = tid; i < 64 * 17; i += 256) m = fmaxf(m, fabsf(W1[i]));
    red[tid] = m; __syncthreads();
    for (int s = 128; s > 0; s >>= 1) { if (tid < s) red[tid] = fmaxf(red[tid], red[tid + s]); __syncthreads(); }
    if (tid == 0) sc_sh[0] = red[0] / QMAXF;
    __syncthreads();

    m = 0.f;
    for (int i = tid; i < 64 * 64; i += 256) m = fmaxf(m, fabsf(W2[i]));
    red[tid] = m; __syncthreads();
    for (int s = 128; s > 0; s >>= 1) { if (tid < s) red[tid] = fmaxf(red[tid], red[tid + s]); __syncthreads(); }
    if (tid == 0) sc_sh[1] = red[0] / QMAXF;
    __syncthreads();

    m = 0.f;
    for (int i = tid; i < 6 * 64; i += 256) m = fmaxf(m, fabsf(W3[i]));
    red[tid] = m; __syncthreads();
    for (int s = 128; s > 0; s >>= 1) { if (tid < s) red[tid] = fmaxf(red[tid], red[tid + s]); __syncthreads(); }
    if (tid == 0) sc_sh[2] = red[0] / QMAXF;
    __syncthreads();
  }
  const float s1 = sc_sh[0], s2 = sc_sh[1], s3 = sc_sh[2];

  const int lane = tid & 63;
  const int bi   = lane & 15;
  const int q    = lane >> 4;
  const int w    = tid >> 6;      // wave id in block

  // ---- weight fragments (integer-valued bf16), once per block ----
  short8 w1f[4];
  #pragma unroll
  for (int t = 0; t < 4; ++t) {
    #pragma unroll
    for (int j = 0; j < 8; ++j) {
      int k = 8 * q + j;
      float wv = (k < 17) ? W1[(16 * t + bi) * 17 + k] : 0.f;
      float wi = rintf(wv / s1);
      wi = fminf(fmaxf(wi, -QMAXF), QMAXF);
      w1f[t][j] = bf16i(wi);
    }
  }
  // K-permutation: eta = 32s + 16(j>>2) + 4q + (j&3) so layer-L C/D regs feed layer-(L+1) B-frags.
  short8 w2f[4][2];
  #pragma unroll
  for (int t = 0; t < 4; ++t) {
    #pragma unroll
    for (int s = 0; s < 2; ++s) {
      #pragma unroll
      for (int j = 0; j < 8; ++j) {
        int eta = 32 * s + 16 * (j >> 2) + 4 * q + (j & 3);
        float wv = W2[(16 * t + bi) * 64 + eta];
        float wi = rintf(wv / s2);
        wi = fminf(fmaxf(wi, -QMAXF), QMAXF);
        w2f[t][s][j] = bf16i(wi);
      }
    }
  }
  short8 w3f[2];
  #pragma unroll
  for (int s = 0; s < 2; ++s) {
    #pragma unroll
    for (int j = 0; j < 8; ++j) {
      int eta = 32 * s + 16 * (j >> 2) + 4 * q + (j & 3);
      float wv = (bi < 6) ? W3[bi * 64 + eta] : 0.f;
      float wi = rintf(wv / s3);
      wi = fminf(fmaxf(wi, -QMAXF), QMAXF);
      w3f[s][j] = bf16i(wi);
    }
  }

  // ---- per-slot biases in integer units ----
  const float g1 = (s1 * step) * istep;
  const float g2 = (s2 * step) * istep;
  const float sc3 = s3 * step;
  float b1s[4][4], b2s[4][4], b3s[4];
  #pragma unroll
  for (int t = 0; t < 4; ++t) {
    #pragma unroll
    for (int r = 0; r < 4; ++r) {
      b1s[t][r] = b1[16 * t + 4 * q + r] * istep;
      b2s[t][r] = b2[16 * t + 4 * q + r] * istep;
    }
  }
  #pragma unroll
  for (int r = 0; r < 4; ++r) {
    int n = 4 * q + r;
    b3s[r] = (n < 6) ? b3[n] : 0.f;
  }

  // ---- main loop: block stages 64 rows/iter via async global->LDS, each wave computes 16 ----
  const int ntiles = B >> 6;                       // 64-row tiles
  const int nIter  = (ntiles + gridDim.x - 1) / gridDim.x;
  const floatx4 zero4 = {0.f, 0.f, 0.f, 0.f};

  auto stage = [&](int t) {
    int tile = (int)blockIdx.x + t * (int)gridDim.x;
    if (tile < ntiles) {
      const float* gp = x + (size_t)tile * 1088;
      float* lp = xs[t & 1];
      async_cp16(gp + w * 256 + lane * 4, lp + w * 256 + lane * 4);   // 4KB via 4 waves
      if (w == 0) async_cp4(gp + 1024 + lane, lp + 1024 + lane);      // 256B tail
    }
  };

  stage(0);
  for (int it = 0; it < nIter; ++it) {
    __syncthreads();                 // publishes xs[it&1]; all waves done with xs[(it+1)&1]
    if (it + 1 < nIter) stage(it + 1);

    int tile = (int)blockIdx.x + it * (int)gridDim.x;
    if (tile >= ntiles) continue;

    const float* xrow = &xs[it & 1][(w * 16 + bi) * 17];

    // input quant -> B-frag: lane holds Xq[row=bi][k=8q+j]
    uint4v ap;
    #pragma unroll
    for (int jp = 0; jp < 4; ++jp) {
      int k0 = 8 * q + 2 * jp;
      float v0 = (k0 < 17)     ? xrow[k0]     : 0.f;
      float v1 = (k0 + 1 < 17) ? xrow[k0 + 1] : 0.f;
      ap[jp] = pack2(qclamp(v0 * istep), qclamp(v1 * istep));
    }
    short8 af = __builtin_bit_cast(short8, ap);

    // L1
    floatx4 c1[4];
    #pragma unroll
    for (int t = 0; t < 4; ++t)
      c1[t] = __builtin_amdgcn_mfma_f32_16x16x32_bf16(w1f[t], af, zero4, 0, 0, 0);

    uint4v h1u[2];
    #pragma unroll
    for (int t = 0; t < 4; ++t) {
      float z0 = qclamp(fmaf(c1[t][0], g1, b1s[t][0]));
      float z1 = qclamp(fmaf(c1[t][1], g1, b1s[t][1]));
      float z2 = qclamp(fmaf(c1[t][2], g1, b1s[t][2]));
      float z3 = qclamp(fmaf(c1[t][3], g1, b1s[t][3]));
      h1u[t >> 1][(t & 1) * 2 + 0] = pack2(z0, z1);
      h1u[t >> 1][(t & 1) * 2 + 1] = pack2(z2, z3);
    }
    short8 h1a = __builtin_bit_cast(short8, h1u[0]);
    short8 h1b = __builtin_bit_cast(short8, h1u[1]);

    // L2 (K=64)
    floatx4 c2[4];
    #pragma unroll
    for (int t = 0; t < 4; ++t) {
      c2[t] = __builtin_amdgcn_mfma_f32_16x16x32_bf16(w2f[t][0], h1a, zero4, 0, 0, 0);
      c2[t] = __builtin_amdgcn_mfma_f32_16x16x32_bf16(w2f[t][1], h1b, c2[t], 0, 0, 0);
    }

    uint4v h2u[2];
    #pragma unroll
    for (int t = 0; t < 4; ++t) {
      float z0 = qclamp(fmaf(c2[t][0], g2, b2s[t][0]));
      float z1 = qclamp(fmaf(c2[t][1], g2, b2s[t][1]));
      float z2 = qclamp(fmaf(c2[t][2], g2, b2s[t][2]));
      float z3 = qclamp(fmaf(c2[t][3], g2, b2s[t][3]));
      h2u[t >> 1][(t & 1) * 2 + 0] = pack2(z0, z1);
      h2u[t >> 1][(t & 1) * 2 + 1] = pack2(z2, z3);
    }
    short8 h2a = __builtin_bit_cast(short8, h2u[0]);
    short8 h2b = __builtin_bit_cast(short8, h2u[1]);

    // L3
    floatx4 c3;
    c3 = __builtin_amdgcn_mfma_f32_16x16x32_bf16(w3f[0], h2a, zero4, 0, 0, 0);
    c3 = __builtin_amdgcn_mfma_f32_16x16x32_bf16(w3f[1], h2b, c3, 0, 0, 0);

    float o0 = fmaf(c3[0], sc3, b3s[0]);
    float o1 = fmaf(c3[1], sc3, b3s[1]);
    float o2 = fmaf(c3[2], sc3, b3s[2]);
    float o3 = fmaf(c3[3], sc3, b3s[3]);
    size_t row = (size_t)tile * 64 + w * 16 + bi;
    float* orow = out + row * 6;
    if (q == 0) {
      *(float2*)(orow)     = make_float2(o0, o1);
      *(float2*)(orow + 2) = make_float2(o2, o3);
    } else if (q == 1) {
      *(float2*)(orow + 4) = make_float2(o0, o1);
    }
  }
}

extern "C" void kernel_launch(void* const* d_in, const int* in_sizes, int n_in,
                              void* d_out, int out_size, void* d_ws, size_t ws_size,
                              hipStream_t stream) {
  const float* x  = (const float*)d_in[0];
  const float* W1 = (const float*)d_in[1];
  const float* b1 = (const float*)d_in[2];
  const float* W2 = (const float*)d_in[3];
  const float* b2 = (const float*)d_in[4];
  const float* W3 = (const float*)d_in[5];
  const float* b3 = (const float*)d_in[6];
  float* out = (float*)d_out;
  const int B = in_sizes[0] / 17;          // 1048576

  dim3 grid(1024), block(256);             // 16 x 64-row tiles per block, fully co-resident
  qmlp_fused<<<grid, block, 0, stream>>>(x, W1, b1, W2, b2, W3, b3, out, B);
}

// Round 4
// 176.745 us; speedup vs baseline: 1.1039x; 1.1039x over previous
//
#include <hip/hip_runtime.h>

// QuantizedActorMLP: x(1M,17) -> quant -> L1(17->64)+quantact -> L2(64->64)+quantact -> L3(64->6)
// Integer-exact bf16 MFMA (ints |n|<=127 exact in bf16, sums < 2^24 exact in fp32 acc).
// R4: EXACTLY the R2 kernel (correctness-verified async double-buffered staging, xs[t&1]
//     array indexing, strided tile mapping) with ONLY the __launch_bounds__ occupancy floor
//     removed — R2's spills (WRITE_SIZE 24.6->99MB at 64 VGPRs) were its sole defect.
//     R3's pointer-swap dbuf miscompiled (absmax 1.0) — do not use loop-carried LDS pointer PHIs.

typedef __attribute__((ext_vector_type(8))) short short8;    // MFMA A/B frag (8 bf16)
typedef __attribute__((ext_vector_type(4))) float floatx4;   // MFMA C/D frag
typedef __attribute__((ext_vector_type(4))) unsigned int uint4v;
typedef unsigned int uint;

__device__ __forceinline__ uint f32bits(float v) { union { float f; uint u; } c; c.f = v; return c.u; }
__device__ __forceinline__ short bf16i(float v) { return (short)(f32bits(v) >> 16); }
// pack two integer-valued f32 -> two bf16 in one uint (low = z0): one v_perm_b32
__device__ __forceinline__ uint pack2(float z0, float z1) {
  return __builtin_amdgcn_perm(f32bits(z1), f32bits(z0), 0x07060302u);
}
// round-to-nearest-even integer clamped to [-127,127]: v_med3 + v_rndne
__device__ __forceinline__ float qclamp(float v) {
  return __builtin_rintf(__builtin_amdgcn_fmed3f(v, -127.f, 127.f));
}

__device__ __forceinline__ void async_cp16(const float* g, float* l) {
  __builtin_amdgcn_global_load_lds((const __attribute__((address_space(1))) void*)g,
                                   (__attribute__((address_space(3))) void*)l, 16, 0, 0);
}
__device__ __forceinline__ void async_cp4(const float* g, float* l) {
  __builtin_amdgcn_global_load_lds((const __attribute__((address_space(1))) void*)g,
                                   (__attribute__((address_space(3))) void*)l, 4, 0, 0);
}

__global__ void __launch_bounds__(256) qmlp_fused(
    const float* __restrict__ x,
    const float* __restrict__ W1, const float* __restrict__ b1,
    const float* __restrict__ W2, const float* __restrict__ b2,
    const float* __restrict__ W3, const float* __restrict__ b3,
    float* __restrict__ out, int B)
{
  constexpr float QMAXF = 127.0f;
  constexpr float SCALE = 1.33f;
  const float step  = SCALE / QMAXF;
  const float istep = QMAXF / SCALE;

  __shared__ __align__(16) float xs[2][1088];   // 64 rows x 17 floats, double-buffered
  __shared__ float red[256];
  __shared__ float sc_sh[3];
  const int tid = threadIdx.x;

  // ---- per-tensor weight scales s = max|W|/127 ----
  {
    float m = 0.f;
    for (int i = tid; i < 64 * 17; i += 256) m = fmaxf(m, fabsf(W1[i]));
    red[tid] = m; __syncthreads();
    for (int s = 128; s > 0; s >>= 1) { if (tid < s) red[tid] = fmaxf(red[tid], red[tid + s]); __syncthreads(); }
    if (tid == 0) sc_sh[0] = red[0] / QMAXF;
    __syncthreads();

    m = 0.f;
    for (int i = tid; i < 64 * 64; i += 256) m = fmaxf(m, fabsf(W2[i]));
    red[tid] = m; __syncthreads();
    for (int s = 128; s > 0; s >>= 1) { if (tid < s) red[tid] = fmaxf(red[tid], red[tid + s]); __syncthreads(); }
    if (tid == 0) sc_sh[1] = red[0] / QMAXF;
    __syncthreads();

    m = 0.f;
    for (int i = tid; i < 6 * 64; i += 256) m = fmaxf(m, fabsf(W3[i]));
    red[tid] = m; __syncthreads();
    for (int s = 128; s > 0; s >>= 1) { if (tid < s) red[tid] = fmaxf(red[tid], red[tid + s]); __syncthreads(); }
    if (tid == 0) sc_sh[2] = red[0] / QMAXF;
    __syncthreads();
  }
  const float s1 = sc_sh[0], s2 = sc_sh[1], s3 = sc_sh[2];

  const int lane = tid & 63;
  const int bi   = lane & 15;
  const int q    = lane >> 4;
  const int w    = tid >> 6;      // wave id in block

  // ---- weight fragments (integer-valued bf16), once per block ----
  short8 w1f[4];
  #pragma unroll
  for (int t = 0; t < 4; ++t) {
    #pragma unroll
    for (int j = 0; j < 8; ++j) {
      int k = 8 * q + j;
      float wv = (k < 17) ? W1[(16 * t + bi) * 17 + k] : 0.f;
      float wi = rintf(wv / s1);
      wi = fminf(fmaxf(wi, -QMAXF), QMAXF);
      w1f[t][j] = bf16i(wi);
    }
  }
  // K-permutation: eta = 32s + 16(j>>2) + 4q + (j&3) so layer-L C/D regs feed layer-(L+1) B-frags.
  short8 w2f[4][2];
  #pragma unroll
  for (int t = 0; t < 4; ++t) {
    #pragma unroll
    for (int s = 0; s < 2; ++s) {
      #pragma unroll
      for (int j = 0; j < 8; ++j) {
        int eta = 32 * s + 16 * (j >> 2) + 4 * q + (j & 3);
        float wv = W2[(16 * t + bi) * 64 + eta];
        float wi = rintf(wv / s2);
        wi = fminf(fmaxf(wi, -QMAXF), QMAXF);
        w2f[t][s][j] = bf16i(wi);
      }
    }
  }
  short8 w3f[2];
  #pragma unroll
  for (int s = 0; s < 2; ++s) {
    #pragma unroll
    for (int j = 0; j < 8; ++j) {
      int eta = 32 * s + 16 * (j >> 2) + 4 * q + (j & 3);
      float wv = (bi < 6) ? W3[bi * 64 + eta] : 0.f;
      float wi = rintf(wv / s3);
      wi = fminf(fmaxf(wi, -QMAXF), QMAXF);
      w3f[s][j] = bf16i(wi);
    }
  }

  // ---- per-slot biases in integer units ----
  const float g1 = (s1 * step) * istep;
  const float g2 = (s2 * step) * istep;
  const float sc3 = s3 * step;
  float b1s[4][4], b2s[4][4], b3s[4];
  #pragma unroll
  for (int t = 0; t < 4; ++t) {
    #pragma unroll
    for (int r = 0; r < 4; ++r) {
      b1s[t][r] = b1[16 * t + 4 * q + r] * istep;
      b2s[t][r] = b2[16 * t + 4 * q + r] * istep;
    }
  }
  #pragma unroll
  for (int r = 0; r < 4; ++r) {
    int n = 4 * q + r;
    b3s[r] = (n < 6) ? b3[n] : 0.f;
  }

  // ---- main loop: block stages 64 rows/iter via async global->LDS, each wave computes 16 ----
  const int ntiles = B >> 6;                       // 64-row tiles
  const int nIter  = (ntiles + gridDim.x - 1) / gridDim.x;
  const floatx4 zero4 = {0.f, 0.f, 0.f, 0.f};

  auto stage = [&](int t) {
    int tile = (int)blockIdx.x + t * (int)gridDim.x;
    if (tile < ntiles) {
      const float* gp = x + (size_t)tile * 1088;
      float* lp = xs[t & 1];
      async_cp16(gp + w * 256 + lane * 4, lp + w * 256 + lane * 4);   // 4KB via 4 waves
      if (w == 0) async_cp4(gp + 1024 + lane, lp + 1024 + lane);      // 256B tail
    }
  };

  stage(0);
  for (int it = 0; it < nIter; ++it) {
    __syncthreads();                 // publishes xs[it&1]; all waves done with xs[(it+1)&1]
    if (it + 1 < nIter) stage(it + 1);

    int tile = (int)blockIdx.x + it * (int)gridDim.x;
    if (tile >= ntiles) continue;

    const float* xrow = &xs[it & 1][(w * 16 + bi) * 17];

    // input quant -> B-frag: lane holds Xq[row=bi][k=8q+j]
    uint4v ap;
    #pragma unroll
    for (int jp = 0; jp < 4; ++jp) {
      int k0 = 8 * q + 2 * jp;
      float v0 = (k0 < 17)     ? xrow[k0]     : 0.f;
      float v1 = (k0 + 1 < 17) ? xrow[k0 + 1] : 0.f;
      ap[jp] = pack2(qclamp(v0 * istep), qclamp(v1 * istep));
    }
    short8 af = __builtin_bit_cast(short8, ap);

    // L1
    floatx4 c1[4];
    #pragma unroll
    for (int t = 0; t < 4; ++t)
      c1[t] = __builtin_amdgcn_mfma_f32_16x16x32_bf16(w1f[t], af, zero4, 0, 0, 0);

    uint4v h1u[2];
    #pragma unroll
    for (int t = 0; t < 4; ++t) {
      float z0 = qclamp(fmaf(c1[t][0], g1, b1s[t][0]));
      float z1 = qclamp(fmaf(c1[t][1], g1, b1s[t][1]));
      float z2 = qclamp(fmaf(c1[t][2], g1, b1s[t][2]));
      float z3 = qclamp(fmaf(c1[t][3], g1, b1s[t][3]));
      h1u[t >> 1][(t & 1) * 2 + 0] = pack2(z0, z1);
      h1u[t >> 1][(t & 1) * 2 + 1] = pack2(z2, z3);
    }
    short8 h1a = __builtin_bit_cast(short8, h1u[0]);
    short8 h1b = __builtin_bit_cast(short8, h1u[1]);

    // L2 (K=64)
    floatx4 c2[4];
    #pragma unroll
    for (int t = 0; t < 4; ++t) {
      c2[t] = __builtin_amdgcn_mfma_f32_16x16x32_bf16(w2f[t][0], h1a, zero4, 0, 0, 0);
      c2[t] = __builtin_amdgcn_mfma_f32_16x16x32_bf16(w2f[t][1], h1b, c2[t], 0, 0, 0);
    }

    uint4v h2u[2];
    #pragma unroll
    for (int t = 0; t < 4; ++t) {
      float z0 = qclamp(fmaf(c2[t][0], g2, b2s[t][0]));
      float z1 = qclamp(fmaf(c2[t][1], g2, b2s[t][1]));
      float z2 = qclamp(fmaf(c2[t][2], g2, b2s[t][2]));
      float z3 = qclamp(fmaf(c2[t][3], g2, b2s[t][3]));
      h2u[t >> 1][(t & 1) * 2 + 0] = pack2(z0, z1);
      h2u[t >> 1][(t & 1) * 2 + 1] = pack2(z2, z3);
    }
    short8 h2a = __builtin_bit_cast(short8, h2u[0]);
    short8 h2b = __builtin_bit_cast(short8, h2u[1]);

    // L3
    floatx4 c3;
    c3 = __builtin_amdgcn_mfma_f32_16x16x32_bf16(w3f[0], h2a, zero4, 0, 0, 0);
    c3 = __builtin_amdgcn_mfma_f32_16x16x32_bf16(w3f[1], h2b, c3, 0, 0, 0);

    float o0 = fmaf(c3[0], sc3, b3s[0]);
    float o1 = fmaf(c3[1], sc3, b3s[1]);
    float o2 = fmaf(c3[2], sc3, b3s[2]);
    float o3 = fmaf(c3[3], sc3, b3s[3]);
    size_t row = (size_t)tile * 64 + w * 16 + bi;
    float* orow = out + row * 6;
    if (q == 0) {
      *(float2*)(orow)     = make_float2(o0, o1);
      *(float2*)(orow + 2) = make_float2(o2, o3);
    } else if (q == 1) {
      *(float2*)(orow + 4) = make_float2(o0, o1);
    }
  }
}

extern "C" void kernel_launch(void* const* d_in, const int* in_sizes, int n_in,
                              void* d_out, int out_size, void* d_ws, size_t ws_size,
                              hipStream_t stream) {
  const float* x  = (const float*)d_in[0];
  const float* W1 = (const float*)d_in[1];
  const float* b1 = (const float*)d_in[2];
  const float* W2 = (const float*)d_in[3];
  const float* b2 = (const float*)d_in[4];
  const float* W3 = (const float*)d_in[5];
  const float* b3 = (const float*)d_in[6];
  float* out = (float*)d_out;
  const int B = in_sizes[0] / 17;          // 1048576

  dim3 grid(1024), block(256);             // 16 x 64-row tiles per block, fully co-resident
  qmlp_fused<<<grid, block, 0, stream>>>(x, W1, b1, W2, b2, W3, b3, out, B);
}

// Round 6
// 170.000 us; speedup vs baseline: 1.1477x; 1.0397x over previous
//
#include <hip/hip_runtime.h>

// QuantizedActorMLP: x(1M,17) -> quant -> L1(17->64)+quantact -> L2(64->64)+quantact -> L3(64->6)
// Integer-exact bf16 MFMA (ints |n|<=127 exact in bf16, sums < 2^24 exact in fp32 acc).
// R6: single kernel (R5's d_ws two-kernel split failed unverifiably -- abandoned).
//     R4's preamble bottleneck (112 uncoalesced weight-gather wave-loads, 64 lines each,
//     + 24-barrier tree reductions, x1024 blocks) fixed in-kernel:
//       - coalesced vector staging of raw W1/W2/W3 into LDS (pitch 65 for W2/W3 to kill
//         16-way bank conflicts on the eta-gather), max-abs fused into the load loop,
//         wave-shuffle reduction + ONE barrier
//       - per-lane fragment gathers read LDS, not global
//       - stage(0) issued before extraction so first x-tile latency hides under the divides
//     Main loop is byte-identical to R4 (correctness-verified, absmax 0.0068).

typedef __attribute__((ext_vector_type(8))) short short8;    // MFMA A/B frag (8 bf16)
typedef __attribute__((ext_vector_type(4))) float floatx4;   // MFMA C/D frag
typedef __attribute__((ext_vector_type(4))) unsigned int uint4v;
typedef unsigned int uint;

__device__ __forceinline__ uint f32bits(float v) { union { float f; uint u; } c; c.f = v; return c.u; }
__device__ __forceinline__ short bf16i(float v) { return (short)(f32bits(v) >> 16); }
// pack two integer-valued f32 -> two bf16 in one uint (low = z0): one v_perm_b32
__device__ __forceinline__ uint pack2(float z0, float z1) {
  return __builtin_amdgcn_perm(f32bits(z1), f32bits(z0), 0x07060302u);
}
// round-to-nearest-even integer clamped to [-127,127]: v_med3 + v_rndne
__device__ __forceinline__ float qclamp(float v) {
  return __builtin_rintf(__builtin_amdgcn_fmed3f(v, -127.f, 127.f));
}

__device__ __forceinline__ void async_cp16(const float* g, float* l) {
  __builtin_amdgcn_global_load_lds((const __attribute__((address_space(1))) void*)g,
                                   (__attribute__((address_space(3))) void*)l, 16, 0, 0);
}
__device__ __forceinline__ void async_cp4(const float* g, float* l) {
  __builtin_amdgcn_global_load_lds((const __attribute__((address_space(1))) void*)g,
                                   (__attribute__((address_space(3))) void*)l, 4, 0, 0);
}

__global__ void __launch_bounds__(256) qmlp_fused(
    const float* __restrict__ x,
    const float* __restrict__ W1, const float* __restrict__ b1,
    const float* __restrict__ W2, const float* __restrict__ b2,
    const float* __restrict__ W3, const float* __restrict__ b3,
    float* __restrict__ out, int B)
{
  constexpr float QMAXF = 127.0f;
  constexpr float SCALE = 1.33f;
  const float step  = SCALE / QMAXF;
  const float istep = QMAXF / SCALE;

  __shared__ __align__(16) float xs[2][1088];   // 64 rows x 17 floats, double-buffered
  __shared__ float wraw1[64 * 17];              // W1 raw, natural pitch 17 (odd -> conflict-free)
  __shared__ float wraw2[64 * 65];              // W2 raw, pitch 65 (pad +1 vs 64)
  __shared__ float wraw3[6 * 65];               // W3 raw rows 0..5, pitch 65
  __shared__ float red[12];                     // per-wave (m1,m2,m3)

  const int tid  = threadIdx.x;
  const int lane = tid & 63;
  const int bi   = lane & 15;
  const int q    = lane >> 4;
  const int w    = tid >> 6;      // wave id in block

  // ---- coalesced staging of raw weights into LDS, max-abs fused into the load ----
  float m1 = 0.f, m2 = 0.f, m3 = 0.f;
  for (int i = tid; i < 64 * 17; i += 256) {
    float v = W1[i]; wraw1[i] = v; m1 = fmaxf(m1, fabsf(v));
  }
  for (int i = tid; i < 64 * 64; i += 256) {
    float v = W2[i]; wraw2[(i >> 6) * 65 + (i & 63)] = v; m2 = fmaxf(m2, fabsf(v));
  }
  for (int i = tid; i < 6 * 64; i += 256) {
    float v = W3[i]; wraw3[(i >> 6) * 65 + (i & 63)] = v; m3 = fmaxf(m3, fabsf(v));
  }
  // wave-level shuffle reduction (width 64), then one-barrier block combine
  #pragma unroll
  for (int off = 32; off > 0; off >>= 1) {
    m1 = fmaxf(m1, __shfl_down(m1, off));
    m2 = fmaxf(m2, __shfl_down(m2, off));
    m3 = fmaxf(m3, __shfl_down(m3, off));
  }
  if (lane == 0) { red[w * 3 + 0] = m1; red[w * 3 + 1] = m2; red[w * 3 + 2] = m3; }
  __syncthreads();                 // publishes red + wraw1/2/3
  float s1 = 0.f, s2 = 0.f, s3 = 0.f;
  #pragma unroll
  for (int i = 0; i < 4; ++i) {
    s1 = fmaxf(s1, red[i * 3 + 0]);
    s2 = fmaxf(s2, red[i * 3 + 1]);
    s3 = fmaxf(s3, red[i * 3 + 2]);
  }
  s1 /= QMAXF; s2 /= QMAXF; s3 /= QMAXF;

  // ---- issue first x-tile staging now; its HBM latency hides under fragment extraction ----
  const int ntiles = B >> 6;                       // 64-row tiles
  const int nIter  = (ntiles + gridDim.x - 1) / gridDim.x;
  auto stage = [&](int t) {
    int tile = (int)blockIdx.x + t * (int)gridDim.x;
    if (tile < ntiles) {
      const float* gp = x + (size_t)tile * 1088;
      float* lp = xs[t & 1];
      async_cp16(gp + w * 256 + lane * 4, lp + w * 256 + lane * 4);   // 4KB via 4 waves
      if (w == 0) async_cp4(gp + 1024 + lane, lp + 1024 + lane);      // 256B tail
    }
  };
  stage(0);

  // ---- weight fragments (integer-valued bf16) from LDS; math identical to R4 ----
  short8 w1f[4];
  #pragma unroll
  for (int t = 0; t < 4; ++t) {
    #pragma unroll
    for (int j = 0; j < 8; ++j) {
      int k = 8 * q + j;
      float wv = (k < 17) ? wraw1[(16 * t + bi) * 17 + k] : 0.f;
      float wi = rintf(wv / s1);
      wi = fminf(fmaxf(wi, -QMAXF), QMAXF);
      w1f[t][j] = bf16i(wi);
    }
  }
  // K-permutation: eta = 32s + 16(j>>2) + 4q + (j&3) so layer-L C/D regs feed layer-(L+1) B-frags.
  short8 w2f[4][2];
  #pragma unroll
  for (int t = 0; t < 4; ++t) {
    #pragma unroll
    for (int s = 0; s < 2; ++s) {
      #pragma unroll
      for (int j = 0; j < 8; ++j) {
        int eta = 32 * s + 16 * (j >> 2) + 4 * q + (j & 3);
        float wv = wraw2[(16 * t + bi) * 65 + eta];
        float wi = rintf(wv / s2);
        wi = fminf(fmaxf(wi, -QMAXF), QMAXF);
        w2f[t][s][j] = bf16i(wi);
      }
    }
  }
  short8 w3f[2];
  #pragma unroll
  for (int s = 0; s < 2; ++s) {
    #pragma unroll
    for (int j = 0; j < 8; ++j) {
      int eta = 32 * s + 16 * (j >> 2) + 4 * q + (j & 3);
      float wv = (bi < 6) ? wraw3[bi * 65 + eta] : 0.f;
      float wi = rintf(wv / s3);
      wi = fminf(fmaxf(wi, -QMAXF), QMAXF);
      w3f[s][j] = bf16i(wi);
    }
  }

  // ---- per-slot biases in integer units (tiny: 9 wave-loads, <=4 lines each) ----
  const float g1 = (s1 * step) * istep;
  const float g2 = (s2 * step) * istep;
  const float sc3 = s3 * step;
  float b1s[4][4], b2s[4][4], b3s[4];
  #pragma unroll
  for (int t = 0; t < 4; ++t) {
    #pragma unroll
    for (int r = 0; r < 4; ++r) {
      b1s[t][r] = b1[16 * t + 4 * q + r] * istep;
      b2s[t][r] = b2[16 * t + 4 * q + r] * istep;
    }
  }
  #pragma unroll
  for (int r = 0; r < 4; ++r) {
    int n = 4 * q + r;
    b3s[r] = (n < 6) ? b3[n] : 0.f;
  }

  // ---- main loop: byte-identical to R4 (verified) ----
  const floatx4 zero4 = {0.f, 0.f, 0.f, 0.f};

  for (int it = 0; it < nIter; ++it) {
    __syncthreads();                 // publishes xs[it&1]; all waves done with xs[(it+1)&1]
    if (it + 1 < nIter) stage(it + 1);

    int tile = (int)blockIdx.x + it * (int)gridDim.x;
    if (tile >= ntiles) continue;

    const float* xrow = &xs[it & 1][(w * 16 + bi) * 17];

    // input quant -> B-frag: lane holds Xq[row=bi][k=8q+j]
    uint4v ap;
    #pragma unroll
    for (int jp = 0; jp < 4; ++jp) {
      int k0 = 8 * q + 2 * jp;
      float v0 = (k0 < 17)     ? xrow[k0]     : 0.f;
      float v1 = (k0 + 1 < 17) ? xrow[k0 + 1] : 0.f;
      ap[jp] = pack2(qclamp(v0 * istep), qclamp(v1 * istep));
    }
    short8 af = __builtin_bit_cast(short8, ap);

    // L1
    floatx4 c1[4];
    #pragma unroll
    for (int t = 0; t < 4; ++t)
      c1[t] = __builtin_amdgcn_mfma_f32_16x16x32_bf16(w1f[t], af, zero4, 0, 0, 0);

    uint4v h1u[2];
    #pragma unroll
    for (int t = 0; t < 4; ++t) {
      float z0 = qclamp(fmaf(c1[t][0], g1, b1s[t][0]));
      float z1 = qclamp(fmaf(c1[t][1], g1, b1s[t][1]));
      float z2 = qclamp(fmaf(c1[t][2], g1, b1s[t][2]));
      float z3 = qclamp(fmaf(c1[t][3], g1, b1s[t][3]));
      h1u[t >> 1][(t & 1) * 2 + 0] = pack2(z0, z1);
      h1u[t >> 1][(t & 1) * 2 + 1] = pack2(z2, z3);
    }
    short8 h1a = __builtin_bit_cast(short8, h1u[0]);
    short8 h1b = __builtin_bit_cast(short8, h1u[1]);

    // L2 (K=64)
    floatx4 c2[4];
    #pragma unroll
    for (int t = 0; t < 4; ++t) {
      c2[t] = __builtin_amdgcn_mfma_f32_16x16x32_bf16(w2f[t][0], h1a, zero4, 0, 0, 0);
      c2[t] = __builtin_amdgcn_mfma_f32_16x16x32_bf16(w2f[t][1], h1b, c2[t], 0, 0, 0);
    }

    uint4v h2u[2];
    #pragma unroll
    for (int t = 0; t < 4; ++t) {
      float z0 = qclamp(fmaf(c2[t][0], g2, b2s[t][0]));
      float z1 = qclamp(fmaf(c2[t][1], g2, b2s[t][1]));
      float z2 = qclamp(fmaf(c2[t][2], g2, b2s[t][2]));
      float z3 = qclamp(fmaf(c2[t][3], g2, b2s[t][3]));
      h2u[t >> 1][(t & 1) * 2 + 0] = pack2(z0, z1);
      h2u[t >> 1][(t & 1) * 2 + 1] = pack2(z2, z3);
    }
    short8 h2a = __builtin_bit_cast(short8, h2u[0]);
    short8 h2b = __builtin_bit_cast(short8, h2u[1]);

    // L3
    floatx4 c3;
    c3 = __builtin_amdgcn_mfma_f32_16x16x32_bf16(w3f[0], h2a, zero4, 0, 0, 0);
    c3 = __builtin_amdgcn_mfma_f32_16x16x32_bf16(w3f[1], h2b, c3, 0, 0, 0);

    float o0 = fmaf(c3[0], sc3, b3s[0]);
    float o1 = fmaf(c3[1], sc3, b3s[1]);
    float o2 = fmaf(c3[2], sc3, b3s[2]);
    float o3 = fmaf(c3[3], sc3, b3s[3]);
    size_t row = (size_t)tile * 64 + w * 16 + bi;
    float* orow = out + row * 6;
    if (q == 0) {
      *(float2*)(orow)     = make_float2(o0, o1);
      *(float2*)(orow + 2) = make_float2(o2, o3);
    } else if (q == 1) {
      *(float2*)(orow + 4) = make_float2(o0, o1);
    }
  }
}

extern "C" void kernel_launch(void* const* d_in, const int* in_sizes, int n_in,
                              void* d_out, int out_size, void* d_ws, size_t ws_size,
                              hipStream_t stream) {
  const float* x  = (const float*)d_in[0];
  const float* W1 = (const float*)d_in[1];
  const float* b1 = (const float*)d_in[2];
  const float* W2 = (const float*)d_in[3];
  const float* b2 = (const float*)d_in[4];
  const float* W3 = (const float*)d_in[5];
  const float* b3 = (const float*)d_in[6];
  float* out = (float*)d_out;
  const int B = in_sizes[0] / 17;          // 1048576

  dim3 grid(1024), block(256);             // 16 x 64-row tiles per block, 4 blocks/CU
  qmlp_fused<<<grid, block, 0, stream>>>(x, W1, b1, W2, b2, W3, b3, out, B);
}

// Round 8
// 152.815 us; speedup vs baseline: 1.2767x; 1.1125x over previous
//
#include <hip/hip_runtime.h>

// QuantizedActorMLP: x(1M,17) -> quant -> L1(17->64)+quantact -> L2(64->64)+quantact -> L3(64->6)
// Integer-exact bf16 MFMA (ints |n|<=127 exact in bf16, sums < 2^24 exact in fp32 acc).
// R8: R7's barrier-free structure with the tile-size bug fixed (R7 used 64-row addressing
//     for 16-row wave-private tiles -> OOB reads -> memory fault). Wave tile = 272 floats.
//     (A) Barrier-free main loop: wave-private LDS slab, register prefetch, no __syncthreads.
//     (B) Preamble: 3 divides + reciprocal-mul quant; vectorized W1 staging.
//     (C) Preamble weight-LDS aliased with slab region.
//     MFMA structure, epilogues, K-permutation identical to R6 (verified, absmax 0.0068).

typedef __attribute__((ext_vector_type(8))) short short8;    // MFMA A/B frag (8 bf16)
typedef __attribute__((ext_vector_type(4))) float floatx4;   // MFMA C/D frag
typedef __attribute__((ext_vector_type(4))) unsigned int uint4v;
typedef unsigned int uint;

__device__ __forceinline__ uint f32bits(float v) { union { float f; uint u; } c; c.f = v; return c.u; }
__device__ __forceinline__ short bf16i(float v) { return (short)(f32bits(v) >> 16); }
// pack two integer-valued f32 -> two bf16 in one uint (low = z0): one v_perm_b32
__device__ __forceinline__ uint pack2(float z0, float z1) {
  return __builtin_amdgcn_perm(f32bits(z1), f32bits(z0), 0x07060302u);
}
// round-to-nearest-even integer clamped to [-127,127]: v_med3 + v_rndne
__device__ __forceinline__ float qclamp(float v) {
  return __builtin_rintf(__builtin_amdgcn_fmed3f(v, -127.f, 127.f));
}

__global__ void __launch_bounds__(256) qmlp_fused(
    const float* __restrict__ x,
    const float* __restrict__ W1, const float* __restrict__ b1,
    const float* __restrict__ W2, const float* __restrict__ b2,
    const float* __restrict__ W3, const float* __restrict__ b3,
    float* __restrict__ out, int B)
{
  constexpr float QMAXF = 127.0f;
  constexpr float SCALE = 1.33f;
  const float step  = SCALE / QMAXF;
  const float istep = QMAXF / SCALE;

  // Aliased LDS: preamble view (wraw1/wraw2/wraw3/red) then, after barrier2,
  // main view (4 wave-private x-slabs of 272 floats, overlapping wraw1 only).
  __shared__ __align__(16) char smem[22608];
  float* wraw1 = (float*)smem;                 // [64*17]  pitch 17 (4352 B)
  float* wraw2 = (float*)(smem + 4352);        // [64*65]  pitch 65 (pad kills gather conflicts)
  float* wraw3 = (float*)(smem + 20992);       // [6*65]   pitch 65
  float* redv  = (float*)(smem + 22552);       // [12]     per-wave (m1,m2,m3)
  float* slabs = (float*)smem;                 // [4][272] main-loop view (aliases wraw1)

  const int tid  = threadIdx.x;
  const int lane = tid & 63;
  const int bi   = lane & 15;
  const int q    = lane >> 4;
  const int w    = tid >> 6;      // wave id in block

  // ---- coalesced staging of raw weights into LDS, max-abs fused into the load ----
  float m1 = 0.f, m2 = 0.f, m3 = 0.f;
  for (int i = tid; i < 272; i += 256) {                       // W1: 1088 floats = 272 float4
    float4 v = ((const float4*)W1)[i];
    ((float4*)wraw1)[i] = v;
    m1 = fmaxf(m1, fmaxf(fmaxf(fabsf(v.x), fabsf(v.y)), fmaxf(fabsf(v.z), fabsf(v.w))));
  }
  for (int i = tid; i < 64 * 64; i += 256) {
    float v = W2[i]; wraw2[(i >> 6) * 65 + (i & 63)] = v; m2 = fmaxf(m2, fabsf(v));
  }
  for (int i = tid; i < 6 * 64; i += 256) {
    float v = W3[i]; wraw3[(i >> 6) * 65 + (i & 63)] = v; m3 = fmaxf(m3, fabsf(v));
  }
  #pragma unroll
  for (int off = 32; off > 0; off >>= 1) {
    m1 = fmaxf(m1, __shfl_down(m1, off));
    m2 = fmaxf(m2, __shfl_down(m2, off));
    m3 = fmaxf(m3, __shfl_down(m3, off));
  }
  if (lane == 0) { redv[w * 3 + 0] = m1; redv[w * 3 + 1] = m2; redv[w * 3 + 2] = m3; }
  __syncthreads();                 // barrier 1: publishes redv + wraw1/2/3
  float s1 = 0.f, s2 = 0.f, s3 = 0.f;
  #pragma unroll
  for (int i = 0; i < 4; ++i) {
    s1 = fmaxf(s1, redv[i * 3 + 0]);
    s2 = fmaxf(s2, redv[i * 3 + 1]);
    s3 = fmaxf(s3, redv[i * 3 + 2]);
  }
  s1 /= QMAXF; s2 /= QMAXF; s3 /= QMAXF;
  const float rs1 = 1.0f / s1, rs2 = 1.0f / s2, rs3 = 1.0f / s3;

  // ---- issue first x prefetch now (HBM latency hides under fragment extraction) ----
  const int ntiles = B >> 4;                                 // 16-row tiles (65536)
  const int wid    = (int)(blockIdx.x * blockDim.x + tid) >> 6;
  const int nw     = (int)(gridDim.x * blockDim.x) >> 6;     // 4096 waves
  const int nIter  = (ntiles + nw - 1) / nw;                 // 16

  // wave tile = 16 rows x 17 floats = 272 floats = 1088 B
  float4 pf = make_float4(0.f, 0.f, 0.f, 0.f);
  float  pt = 0.f;
  {
    int gtile = wid;
    if (gtile < ntiles) {
      const float* gp = x + (size_t)gtile * 272;
      pf = *(const float4*)(gp + lane * 4);                  // 256 floats
      if (lane < 16) pt = gp[256 + lane];                    // 16-float tail
    }
  }

  // ---- weight fragments (integer-valued bf16) from LDS (reciprocal-mul quant) ----
  short8 w1f[4];
  #pragma unroll
  for (int t = 0; t < 4; ++t) {
    #pragma unroll
    for (int j = 0; j < 8; ++j) {
      int k = 8 * q + j;
      float wv = (k < 17) ? wraw1[(16 * t + bi) * 17 + k] : 0.f;
      float wi = fminf(fmaxf(rintf(wv * rs1), -QMAXF), QMAXF);
      w1f[t][j] = bf16i(wi);
    }
  }
  // K-permutation: eta = 32s + 16(j>>2) + 4q + (j&3) so layer-L C/D regs feed layer-(L+1) B-frags.
  short8 w2f[4][2];
  #pragma unroll
  for (int t = 0; t < 4; ++t) {
    #pragma unroll
    for (int s = 0; s < 2; ++s) {
      #pragma unroll
      for (int j = 0; j < 8; ++j) {
        int eta = 32 * s + 16 * (j >> 2) + 4 * q + (j & 3);
        float wv = wraw2[(16 * t + bi) * 65 + eta];
        float wi = fminf(fmaxf(rintf(wv * rs2), -QMAXF), QMAXF);
        w2f[t][s][j] = bf16i(wi);
      }
    }
  }
  short8 w3f[2];
  #pragma unroll
  for (int s = 0; s < 2; ++s) {
    #pragma unroll
    for (int j = 0; j < 8; ++j) {
      int eta = 32 * s + 16 * (j >> 2) + 4 * q + (j & 3);
      float wv = (bi < 6) ? wraw3[bi * 65 + eta] : 0.f;
      float wi = fminf(fmaxf(rintf(wv * rs3), -QMAXF), QMAXF);
      w3f[s][j] = bf16i(wi);
    }
  }

  // ---- per-slot biases in integer units (few lines each, L2-hot) ----
  const float g1 = (s1 * step) * istep;
  const float g2 = (s2 * step) * istep;
  const float sc3 = s3 * step;
  float b1s[4][4], b2s[4][4], b3s[4];
  #pragma unroll
  for (int t = 0; t < 4; ++t) {
    #pragma unroll
    for (int r = 0; r < 4; ++r) {
      b1s[t][r] = b1[16 * t + 4 * q + r] * istep;
      b2s[t][r] = b2[16 * t + 4 * q + r] * istep;
    }
  }
  #pragma unroll
  for (int r = 0; r < 4; ++r) {
    int n = 4 * q + r;
    b3s[r] = (n < 6) ? b3[n] : 0.f;
  }

  __syncthreads();                 // barrier 2: all waves done reading wraw*; slabs may be written

  // ---- barrier-free main loop: wave-private slab, explicit register prefetch ----
  float* myslab = slabs + w * 272;
  const floatx4 zero4 = {0.f, 0.f, 0.f, 0.f};

  for (int it = 0; it < nIter; ++it) {
    int gtile = wid + it * nw;

    // commit current prefetch into my slab (wave-internal lgkmcnt ordering only)
    *(float4*)(myslab + lane * 4) = pf;
    if (lane < 16) myslab[256 + lane] = pt;

    // issue next prefetch; in flight during this iteration's compute
    if (it + 1 < nIter) {
      int nt = wid + (it + 1) * nw;
      if (nt < ntiles) {
        const float* gp = x + (size_t)nt * 272;
        pf = *(const float4*)(gp + lane * 4);
        if (lane < 16) pt = gp[256 + lane];
      }
    }

    if (gtile >= ntiles) continue;

    const float* xrow = myslab + bi * 17;

    // input quant -> B-frag: lane holds Xq[row=bi][k=8q+j]
    uint4v ap;
    #pragma unroll
    for (int jp = 0; jp < 4; ++jp) {
      int k0 = 8 * q + 2 * jp;
      float v0 = (k0 < 17)     ? xrow[k0]     : 0.f;
      float v1 = (k0 + 1 < 17) ? xrow[k0 + 1] : 0.f;
      ap[jp] = pack2(qclamp(v0 * istep), qclamp(v1 * istep));
    }
    short8 af = __builtin_bit_cast(short8, ap);

    // L1
    floatx4 c1[4];
    #pragma unroll
    for (int t = 0; t < 4; ++t)
      c1[t] = __builtin_amdgcn_mfma_f32_16x16x32_bf16(w1f[t], af, zero4, 0, 0, 0);

    uint4v h1u[2];
    #pragma unroll
    for (int t = 0; t < 4; ++t) {
      float z0 = qclamp(fmaf(c1[t][0], g1, b1s[t][0]));
      float z1 = qclamp(fmaf(c1[t][1], g1, b1s[t][1]));
      float z2 = qclamp(fmaf(c1[t][2], g1, b1s[t][2]));
      float z3 = qclamp(fmaf(c1[t][3], g1, b1s[t][3]));
      h1u[t >> 1][(t & 1) * 2 + 0] = pack2(z0, z1);
      h1u[t >> 1][(t & 1) * 2 + 1] = pack2(z2, z3);
    }
    short8 h1a = __builtin_bit_cast(short8, h1u[0]);
    short8 h1b = __builtin_bit_cast(short8, h1u[1]);

    // L2 (K=64)
    floatx4 c2[4];
    #pragma unroll
    for (int t = 0; t < 4; ++t) {
      c2[t] = __builtin_amdgcn_mfma_f32_16x16x32_bf16(w2f[t][0], h1a, zero4, 0, 0, 0);
      c2[t] = __builtin_amdgcn_mfma_f32_16x16x32_bf16(w2f[t][1], h1b, c2[t], 0, 0, 0);
    }

    uint4v h2u[2];
    #pragma unroll
    for (int t = 0; t < 4; ++t) {
      float z0 = qclamp(fmaf(c2[t][0], g2, b2s[t][0]));
      float z1 = qclamp(fmaf(c2[t][1], g2, b2s[t][1]));
      float z2 = qclamp(fmaf(c2[t][2], g2, b2s[t][2]));
      float z3 = qclamp(fmaf(c2[t][3], g2, b2s[t][3]));
      h2u[t >> 1][(t & 1) * 2 + 0] = pack2(z0, z1);
      h2u[t >> 1][(t & 1) * 2 + 1] = pack2(z2, z3);
    }
    short8 h2a = __builtin_bit_cast(short8, h2u[0]);
    short8 h2b = __builtin_bit_cast(short8, h2u[1]);

    // L3
    floatx4 c3;
    c3 = __builtin_amdgcn_mfma_f32_16x16x32_bf16(w3f[0], h2a, zero4, 0, 0, 0);
    c3 = __builtin_amdgcn_mfma_f32_16x16x32_bf16(w3f[1], h2b, c3, 0, 0, 0);

    float o0 = fmaf(c3[0], sc3, b3s[0]);
    float o1 = fmaf(c3[1], sc3, b3s[1]);
    float o2 = fmaf(c3[2], sc3, b3s[2]);
    float o3 = fmaf(c3[3], sc3, b3s[3]);
    size_t row = (size_t)gtile * 16 + bi;
    float* orow = out + row * 6;
    if (q == 0) {
      *(float2*)(orow)     = make_float2(o0, o1);
      *(float2*)(orow + 2) = make_float2(o2, o3);
    } else if (q == 1) {
      *(float2*)(orow + 4) = make_float2(o0, o1);
    }
  }
}

extern "C" void kernel_launch(void* const* d_in, const int* in_sizes, int n_in,
                              void* d_out, int out_size, void* d_ws, size_t ws_size,
                              hipStream_t stream) {
  const float* x  = (const float*)d_in[0];
  const float* W1 = (const float*)d_in[1];
  const float* b1 = (const float*)d_in[2];
  const float* W2 = (const float*)d_in[3];
  const float* b2 = (const float*)d_in[4];
  const float* W3 = (const float*)d_in[5];
  const float* b3 = (const float*)d_in[6];
  float* out = (float*)d_out;
  const int B = in_sizes[0] / 17;          // 1048576

  dim3 grid(1024), block(256);             // 4096 waves x 16 iterations, 4 blocks/CU
  qmlp_fused<<<grid, block, 0, stream>>>(x, W1, b1, W2, b2, W3, b3, out, B);
}

// Round 9
// 149.080 us; speedup vs baseline: 1.3087x; 1.0251x over previous
//
#include <hip/hip_runtime.h>

// QuantizedActorMLP: x(1M,17) -> quant -> L1(17->64)+quantact -> L2(64->64)+quantact -> L3(64->6)
// Integer-exact bf16 MFMA (ints |n|<=127 exact in bf16, sums < 2^24 exact in fp32 acc).
// R9: R8 minus the main-loop LDS round-trip. B-frag inputs are loaded per-lane DIRECTLY
//     from global (lane(bi,q<2) reads 8 contiguous dwords of row bi; q==2 reads k=16 only;
//     q==3 is all padding -> no load), register double-buffered one iteration ahead.
//     Removes ds_write/ds_read legs (~240cyc chained latency/iter) + slab commit ordering.
//     LDS = preamble weight staging only; ONE barrier in the whole kernel.
//     Preamble + MFMA structure + epilogues identical to R8 (verified, absmax 0.0068).

typedef __attribute__((ext_vector_type(8))) short short8;    // MFMA A/B frag (8 bf16)
typedef __attribute__((ext_vector_type(4))) float floatx4;   // MFMA C/D frag
typedef __attribute__((ext_vector_type(4))) unsigned int uint4v;
typedef unsigned int uint;

__device__ __forceinline__ uint f32bits(float v) { union { float f; uint u; } c; c.f = v; return c.u; }
__device__ __forceinline__ short bf16i(float v) { return (short)(f32bits(v) >> 16); }
// pack two integer-valued f32 -> two bf16 in one uint (low = z0): one v_perm_b32
__device__ __forceinline__ uint pack2(float z0, float z1) {
  return __builtin_amdgcn_perm(f32bits(z1), f32bits(z0), 0x07060302u);
}
// round-to-nearest-even integer clamped to [-127,127]: v_med3 + v_rndne
__device__ __forceinline__ float qclamp(float v) {
  return __builtin_rintf(__builtin_amdgcn_fmed3f(v, -127.f, 127.f));
}

__global__ void __launch_bounds__(256) qmlp_fused(
    const float* __restrict__ x,
    const float* __restrict__ W1, const float* __restrict__ b1,
    const float* __restrict__ W2, const float* __restrict__ b2,
    const float* __restrict__ W3, const float* __restrict__ b3,
    float* __restrict__ out, int B)
{
  constexpr float QMAXF = 127.0f;
  constexpr float SCALE = 1.33f;
  const float step  = SCALE / QMAXF;
  const float istep = QMAXF / SCALE;

  __shared__ __align__(16) float wraw1[64 * 17];   // W1 raw, pitch 17
  __shared__ float wraw2[64 * 65];                 // W2 raw, pitch 65 (pad kills gather conflicts)
  __shared__ float wraw3[6 * 65];                  // W3 raw, pitch 65
  __shared__ float redv[12];                       // per-wave (m1,m2,m3)

  const int tid  = threadIdx.x;
  const int lane = tid & 63;
  const int bi   = lane & 15;
  const int q    = lane >> 4;

  // ---- coalesced staging of raw weights into LDS, max-abs fused into the load ----
  float m1 = 0.f, m2 = 0.f, m3 = 0.f;
  for (int i = tid; i < 272; i += 256) {                       // W1: 1088 floats = 272 float4
    float4 v = ((const float4*)W1)[i];
    ((float4*)wraw1)[i] = v;
    m1 = fmaxf(m1, fmaxf(fmaxf(fabsf(v.x), fabsf(v.y)), fmaxf(fabsf(v.z), fabsf(v.w))));
  }
  for (int i = tid; i < 64 * 64; i += 256) {
    float v = W2[i]; wraw2[(i >> 6) * 65 + (i & 63)] = v; m2 = fmaxf(m2, fabsf(v));
  }
  for (int i = tid; i < 6 * 64; i += 256) {
    float v = W3[i]; wraw3[(i >> 6) * 65 + (i & 63)] = v; m3 = fmaxf(m3, fabsf(v));
  }
  #pragma unroll
  for (int off = 32; off > 0; off >>= 1) {
    m1 = fmaxf(m1, __shfl_down(m1, off));
    m2 = fmaxf(m2, __shfl_down(m2, off));
    m3 = fmaxf(m3, __shfl_down(m3, off));
  }
  if (lane == 0) {
    int w4 = tid >> 6;
    redv[w4 * 3 + 0] = m1; redv[w4 * 3 + 1] = m2; redv[w4 * 3 + 2] = m3;
  }
  __syncthreads();                 // the ONLY barrier: publishes redv + wraw1/2/3
  float s1 = 0.f, s2 = 0.f, s3 = 0.f;
  #pragma unroll
  for (int i = 0; i < 4; ++i) {
    s1 = fmaxf(s1, redv[i * 3 + 0]);
    s2 = fmaxf(s2, redv[i * 3 + 1]);
    s3 = fmaxf(s3, redv[i * 3 + 2]);
  }
  s1 /= QMAXF; s2 /= QMAXF; s3 /= QMAXF;
  const float rs1 = 1.0f / s1, rs2 = 1.0f / s2, rs3 = 1.0f / s3;

  const int ntiles = B >> 4;                                 // 16-row tiles (65536)
  const int wid    = (int)(blockIdx.x * blockDim.x + tid) >> 6;
  const int nw     = (int)(gridDim.x * blockDim.x) >> 6;     // 4096 waves
  const int nIter  = (ntiles + nw - 1) / nw;                 // 16

  // per-lane direct B-frag input load: lane(bi,q) needs x[tile*16+bi][8q..8q+7]
  auto load_inputs = [&](int gtile, float xv[8]) {
    const float* rowp = x + (size_t)gtile * 272 + bi * 17;
    if (q < 2) {
      #pragma unroll
      for (int j = 0; j < 8; ++j) xv[j] = rowp[8 * q + j];
    } else {
      xv[0] = (q == 2) ? rowp[16] : 0.f;
      #pragma unroll
      for (int j = 1; j < 8; ++j) xv[j] = 0.f;
    }
  };

  // ---- issue first x loads now (latency hides under fragment extraction) ----
  float xv[8];
  if (wid < ntiles) {
    load_inputs(wid, xv);
  } else {
    #pragma unroll
    for (int j = 0; j < 8; ++j) xv[j] = 0.f;
  }

  // ---- weight fragments (integer-valued bf16) from LDS (reciprocal-mul quant) ----
  short8 w1f[4];
  #pragma unroll
  for (int t = 0; t < 4; ++t) {
    #pragma unroll
    for (int j = 0; j < 8; ++j) {
      int k = 8 * q + j;
      float wv = (k < 17) ? wraw1[(16 * t + bi) * 17 + k] : 0.f;
      float wi = fminf(fmaxf(rintf(wv * rs1), -QMAXF), QMAXF);
      w1f[t][j] = bf16i(wi);
    }
  }
  // K-permutation: eta = 32s + 16(j>>2) + 4q + (j&3) so layer-L C/D regs feed layer-(L+1) B-frags.
  short8 w2f[4][2];
  #pragma unroll
  for (int t = 0; t < 4; ++t) {
    #pragma unroll
    for (int s = 0; s < 2; ++s) {
      #pragma unroll
      for (int j = 0; j < 8; ++j) {
        int eta = 32 * s + 16 * (j >> 2) + 4 * q + (j & 3);
        float wv = wraw2[(16 * t + bi) * 65 + eta];
        float wi = fminf(fmaxf(rintf(wv * rs2), -QMAXF), QMAXF);
        w2f[t][s][j] = bf16i(wi);
      }
    }
  }
  short8 w3f[2];
  #pragma unroll
  for (int s = 0; s < 2; ++s) {
    #pragma unroll
    for (int j = 0; j < 8; ++j) {
      int eta = 32 * s + 16 * (j >> 2) + 4 * q + (j & 3);
      float wv = (bi < 6) ? wraw3[bi * 65 + eta] : 0.f;
      float wi = fminf(fmaxf(rintf(wv * rs3), -QMAXF), QMAXF);
      w3f[s][j] = bf16i(wi);
    }
  }

  // ---- per-slot biases in integer units (few lines each, L2-hot) ----
  const float g1 = (s1 * step) * istep;
  const float g2 = (s2 * step) * istep;
  const float sc3 = s3 * step;
  float b1s[4][4], b2s[4][4], b3s[4];
  #pragma unroll
  for (int t = 0; t < 4; ++t) {
    #pragma unroll
    for (int r = 0; r < 4; ++r) {
      b1s[t][r] = b1[16 * t + 4 * q + r] * istep;
      b2s[t][r] = b2[16 * t + 4 * q + r] * istep;
    }
  }
  #pragma unroll
  for (int r = 0; r < 4; ++r) {
    int n = 4 * q + r;
    b3s[r] = (n < 6) ? b3[n] : 0.f;
  }

  // ---- main loop: no LDS, no barriers; register double-buffered direct loads ----
  const floatx4 zero4 = {0.f, 0.f, 0.f, 0.f};

  for (int it = 0; it < nIter; ++it) {
    int gtile = wid + it * nw;

    // issue next iteration's loads first: a full iteration of compute hides them
    float xn[8];
    {
      int nt = wid + (it + 1) * nw;
      if (it + 1 < nIter && nt < ntiles) {
        load_inputs(nt, xn);
      } else {
        #pragma unroll
        for (int j = 0; j < 8; ++j) xn[j] = 0.f;
      }
    }

    if (gtile < ntiles) {
      // input quant -> B-frag: lane holds Xq[row=bi][k=8q+j]
      uint4v ap;
      #pragma unroll
      for (int jp = 0; jp < 4; ++jp)
        ap[jp] = pack2(qclamp(xv[2 * jp] * istep), qclamp(xv[2 * jp + 1] * istep));
      short8 af = __builtin_bit_cast(short8, ap);

      // L1
      floatx4 c1[4];
      #pragma unroll
      for (int t = 0; t < 4; ++t)
        c1[t] = __builtin_amdgcn_mfma_f32_16x16x32_bf16(w1f[t], af, zero4, 0, 0, 0);

      uint4v h1u[2];
      #pragma unroll
      for (int t = 0; t < 4; ++t) {
        float z0 = qclamp(fmaf(c1[t][0], g1, b1s[t][0]));
        float z1 = qclamp(fmaf(c1[t][1], g1, b1s[t][1]));
        float z2 = qclamp(fmaf(c1[t][2], g1, b1s[t][2]));
        float z3 = qclamp(fmaf(c1[t][3], g1, b1s[t][3]));
        h1u[t >> 1][(t & 1) * 2 + 0] = pack2(z0, z1);
        h1u[t >> 1][(t & 1) * 2 + 1] = pack2(z2, z3);
      }
      short8 h1a = __builtin_bit_cast(short8, h1u[0]);
      short8 h1b = __builtin_bit_cast(short8, h1u[1]);

      // L2 (K=64)
      floatx4 c2[4];
      #pragma unroll
      for (int t = 0; t < 4; ++t) {
        c2[t] = __builtin_amdgcn_mfma_f32_16x16x32_bf16(w2f[t][0], h1a, zero4, 0, 0, 0);
        c2[t] = __builtin_amdgcn_mfma_f32_16x16x32_bf16(w2f[t][1], h1b, c2[t], 0, 0, 0);
      }

      uint4v h2u[2];
      #pragma unroll
      for (int t = 0; t < 4; ++t) {
        float z0 = qclamp(fmaf(c2[t][0], g2, b2s[t][0]));
        float z1 = qclamp(fmaf(c2[t][1], g2, b2s[t][1]));
        float z2 = qclamp(fmaf(c2[t][2], g2, b2s[t][2]));
        float z3 = qclamp(fmaf(c2[t][3], g2, b2s[t][3]));
        h2u[t >> 1][(t & 1) * 2 + 0] = pack2(z0, z1);
        h2u[t >> 1][(t & 1) * 2 + 1] = pack2(z2, z3);
      }
      short8 h2a = __builtin_bit_cast(short8, h2u[0]);
      short8 h2b = __builtin_bit_cast(short8, h2u[1]);

      // L3
      floatx4 c3;
      c3 = __builtin_amdgcn_mfma_f32_16x16x32_bf16(w3f[0], h2a, zero4, 0, 0, 0);
      c3 = __builtin_amdgcn_mfma_f32_16x16x32_bf16(w3f[1], h2b, c3, 0, 0, 0);

      float o0 = fmaf(c3[0], sc3, b3s[0]);
      float o1 = fmaf(c3[1], sc3, b3s[1]);
      float o2 = fmaf(c3[2], sc3, b3s[2]);
      float o3 = fmaf(c3[3], sc3, b3s[3]);
      size_t row = (size_t)gtile * 16 + bi;
      float* orow = out + row * 6;
      if (q == 0) {
        *(float2*)(orow)     = make_float2(o0, o1);
        *(float2*)(orow + 2) = make_float2(o2, o3);
      } else if (q == 1) {
        *(float2*)(orow + 4) = make_float2(o0, o1);
      }
    }

    #pragma unroll
    for (int j = 0; j < 8; ++j) xv[j] = xn[j];
  }
}

extern "C" void kernel_launch(void* const* d_in, const int* in_sizes, int n_in,
                              void* d_out, int out_size, void* d_ws, size_t ws_size,
                              hipStream_t stream) {
  const float* x  = (const float*)d_in[0];
  const float* W1 = (const float*)d_in[1];
  const float* b1 = (const float*)d_in[2];
  const float* W2 = (const float*)d_in[3];
  const float* b2 = (const float*)d_in[4];
  const float* W3 = (const float*)d_in[5];
  const float* b3 = (const float*)d_in[6];
  float* out = (float*)d_out;
  const int B = in_sizes[0] / 17;          // 1048576

  dim3 grid(1024), block(256);             // 4096 waves x 16 iterations, 4 blocks/CU
  qmlp_fused<<<grid, block, 0, stream>>>(x, W1, b1, W2, b2, W3, b3, out, B);
}